// Round 5
// baseline (372.372 us; speedup 1.0000x reference)
//
#include <hip/hip_runtime.h>

#define B_   4
#define N_   4096
#define NH   16
#define DH   64
#define HID  1024
#define NC3  3072
#define M_   256
#define BH   64
#define SCALE 0.125f
#define EPS   1e-3f
#define CH2  8
#define CH3  16

typedef _Float16 half8  __attribute__((ext_vector_type(8)));
typedef _Float16 half4v __attribute__((ext_vector_type(4)));
typedef float floatx4   __attribute__((ext_vector_type(4)));

#define GLD_LDS16(gptr, lds_base) \
  __builtin_amdgcn_global_load_lds((const __attribute__((address_space(1))) void*)(gptr), \
                                   (__attribute__((address_space(3))) void*)(lds_base), 16, 0, 0)

// barrier that is also a compiler memory fence (no sched_barrier pinning)
#define SBAR() asm volatile("s_barrier" ::: "memory")

// ---------- xh = (f16) x ----------
__global__ __launch_bounds__(256) void convert_xh(
    const float* __restrict__ x, _Float16* __restrict__ xh)
{
    const size_t i = ((size_t)blockIdx.x * 256 + threadIdx.x) * 8;
    float4 a = *(const float4*)(x + i);
    float4 b = *(const float4*)(x + i + 4);
    half8 h;
    h[0] = (_Float16)a.x; h[1] = (_Float16)a.y; h[2] = (_Float16)a.z; h[3] = (_Float16)a.w;
    h[4] = (_Float16)b.x; h[5] = (_Float16)b.y; h[6] = (_Float16)b.z; h[7] = (_Float16)b.w;
    *(half8*)(xh + i) = h;
}

// ---------- wT[n][k] = (f16) w[k][n]  (q/k bands pre-scaled by d^-0.25) ----------
__global__ __launch_bounds__(256) void convert_wT(
    const float* __restrict__ w, _Float16* __restrict__ wT)
{
    __shared__ float t[64][65];
    const int tid = threadIdx.x;
    const int kb = blockIdx.y * 64, nb = blockIdx.x * 64;
    const int c = tid & 63, r0 = tid >> 6;
#pragma unroll
    for (int rr = 0; rr < 64; rr += 4)
        t[rr + r0][c] = w[(size_t)(kb + rr + r0) * NC3 + nb + c];
    __syncthreads();
    const float sc = (nb < 2048) ? SCALE : 1.0f;   // band is 64-wide: uniform per block
#pragma unroll
    for (int rr = 0; rr < 64; rr += 4)
        wT[(size_t)(nb + rr + r0) * HID + kb + c] = (_Float16)(t[c][rr + r0] * sc);
}

// ---------- projh = (f16) proj ----------
__global__ __launch_bounds__(256) void convert_projh(
    const float* __restrict__ proj, _Float16* __restrict__ projh)
{
    const int i = blockIdx.x * 256 + threadIdx.x;
    projh[i] = (_Float16)proj[i];
}

// ---------- Phase 1: qkv GEMM, 256x256 tile, BK=64, 8-wave, 2-barrier/tile pipeline ----------
// (round-2 verified structure: best measured 124.8 us)
__device__ __forceinline__ void stage_tile_qkv(
    const _Float16* __restrict__ xh, const _Float16* __restrict__ wT,
    int row0, int col0, int kt, char* ab, char* bb, int wv, int srow, int sblk)
{
    const size_t ko = (size_t)kt * 64;
#pragma unroll
    for (int s = 0; s < 4; ++s) {
        const int r = s * 64 + srow;
        GLD_LDS16(xh + (size_t)(row0 + r) * HID + ko + 8 * sblk, ab + s * 8192 + wv * 1024);
        GLD_LDS16(wT + (size_t)(col0 + r) * HID + ko + 8 * sblk, bb + s * 8192 + wv * 1024);
    }
}

__global__ __launch_bounds__(512, 2) void gemm_qkv_mfma(
    const _Float16* __restrict__ xh, const _Float16* __restrict__ wT,
    const float* __restrict__ bias,
    _Float16* __restrict__ qh, _Float16* __restrict__ kh, _Float16* __restrict__ vTh)
{
    __shared__ __align__(16) char smem[131072];

    const int tid  = threadIdx.x;
    const int lane = tid & 63;
    const int wv   = tid >> 6;       // 0..7
    const int wm   = wv >> 2;        // 0..1  -> rows wm*128..+128
    const int wn   = wv & 3;         // 0..3  -> cols wn*64..+64
    const int lr   = lane & 15;
    const int lg   = lane >> 4;
    const int lr7  = lr & 7;

    // XCD-aware bijective swizzle: 768 tiles, 8 XCDs, 96 tiles per XCD chunk
    const int bid  = blockIdx.x;
    const int tile = ((bid & 7) * 96) + (bid >> 3);
    const int tm   = tile / 12;
    const int tn   = tile - tm * 12;
    const int row0 = tm * 256;
    const int col0 = tn * 256;

    // staging geometry: per issue (8192 B), wave wv covers 8 rows; lane -> (row, phys blk)
    const int srow = 8 * wv + (lane >> 3);
    const int sblk = (lane & 7) ^ (lane >> 3);   // logical block for linear phys slot (lane&7)

    char* buf0A = smem;
    char* buf0B = smem + 32768;
    char* buf1A = smem + 65536;
    char* buf1B = smem + 98304;

    floatx4 acc[8][4] = {};

    // prologue: tiles 0 and 1 in flight (16 loads per wave)
    stage_tile_qkv(xh, wT, row0, col0, 0, buf0A, buf0B, wv, srow, sblk);
    stage_tile_qkv(xh, wT, row0, col0, 1, buf1A, buf1B, wv, srow, sblk);

    for (int t = 0; t < 16; ++t) {
        // counted vmcnt: tile t's 8 loads landed; next tile's 8 stay in flight
        if (t < 15) asm volatile("s_waitcnt vmcnt(8)" ::: "memory");
        else        asm volatile("s_waitcnt vmcnt(0)" ::: "memory");
        SBAR();

        char* ab = (t & 1) ? buf1A : buf0A;
        char* bb = (t & 1) ? buf1B : buf0B;

        // ---- fragments, K-half 0 (k 0..31) ----
        half8 a0[8], b0[4];
#pragma unroll
        for (int i = 0; i < 8; ++i)
            a0[i] = *(const half8*)(ab + (wm * 128 + 16 * i + lr) * 128 + ((lg ^ lr7) * 16));
#pragma unroll
        for (int j = 0; j < 4; ++j)
            b0[j] = *(const half8*)(bb + (wn * 64 + 16 * j + lr) * 128 + ((lg ^ lr7) * 16));

        __builtin_amdgcn_s_setprio(1);
#pragma unroll
        for (int i = 0; i < 8; ++i)
#pragma unroll
            for (int j = 0; j < 4; ++j)
                acc[i][j] = __builtin_amdgcn_mfma_f32_16x16x32_f16(a0[i], b0[j], acc[i][j], 0, 0, 0);
        __builtin_amdgcn_s_setprio(0);

        // ---- fragments, K-half 1 (k 32..63) ----
        half8 a1[8], b1[4];
#pragma unroll
        for (int i = 0; i < 8; ++i)
            a1[i] = *(const half8*)(ab + (wm * 128 + 16 * i + lr) * 128 + (((4 + lg) ^ lr7) * 16));
#pragma unroll
        for (int j = 0; j < 4; ++j)
            b1[j] = *(const half8*)(bb + (wn * 64 + 16 * j + lr) * 128 + (((4 + lg) ^ lr7) * 16));

        // this wave's LDS reads of buf[t&1] complete -> all waves done -> buffer is free
        asm volatile("s_waitcnt lgkmcnt(0)" ::: "memory");
        SBAR();
        if (t < 14)
            stage_tile_qkv(xh, wT, row0, col0, t + 2, ab, bb, wv, srow, sblk);

        __builtin_amdgcn_s_setprio(1);
#pragma unroll
        for (int i = 0; i < 8; ++i)
#pragma unroll
            for (int j = 0; j < 4; ++j)
                acc[i][j] = __builtin_amdgcn_mfma_f32_16x16x32_f16(a1[i], b1[j], acc[i][j], 0, 0, 0);
        __builtin_amdgcn_s_setprio(0);
    }

    // ---- epilogue: bias + split q/k/v ----
#pragma unroll
    for (int j = 0; j < 4; ++j) {
        const int col = col0 + wn * 64 + 16 * j + lr;
        const int which = col >> 10;
        const int h = (col >> 6) & 15;
        const int d = col & 63;
        const float bb2 = bias[col] * ((which < 2) ? SCALE : 1.0f);
        if (which == 2) {
#pragma unroll
            for (int i = 0; i < 8; ++i) {
                const int m0 = row0 + wm * 128 + 16 * i + 4 * lg;
                const int bi = m0 >> 12, n0 = m0 & (N_ - 1);
                half4v hv;
#pragma unroll
                for (int rg = 0; rg < 4; ++rg) hv[rg] = (_Float16)(acc[i][j][rg] + bb2);
                *(half4v*)(vTh + ((size_t)(bi * NH + h) * DH + d) * N_ + n0) = hv;
            }
        } else {
            _Float16* dst = (which == 0) ? qh : kh;
#pragma unroll
            for (int i = 0; i < 8; ++i)
#pragma unroll
                for (int rg = 0; rg < 4; ++rg) {
                    const int m = row0 + wm * 128 + 16 * i + 4 * lg + rg;
                    const int bi = m >> 12, n = m & (N_ - 1);
                    dst[((size_t)(bi * NH + h) * N_ + n) * DH + d] =
                        (_Float16)(acc[i][j][rg] + bb2);
                }
        }
    }
}

// ---------- Phase 2: per (chunk,bh): ctxT_part[d][m] = sum_n vT[d][n] * k'[n][m] ----------
// Double-buffered K/V staging: one barrier per tile; tile t+1's global_load_lds
// fly under tile t's compute (T3-minimum pattern). LDS 64 KB; grid 512 = 2 blocks/CU
// both before and after (no occupancy cost).
__global__ __launch_bounds__(256) void kv_ctx_mfma(
    const _Float16* __restrict__ kh, const _Float16* __restrict__ vTh,
    const _Float16* __restrict__ projh,
    float* __restrict__ ctx_part, float* __restrict__ ksum_part)
{
    __shared__ __align__(16) _Float16 Kt[2][64 * 64];   // [n][d] swizzled
    __shared__ __align__(16) _Float16 Vt[2][64 * 64];   // [d][n] swizzled
    __shared__ __align__(16) _Float16 Sp[256 * 64];     // [m][n] swizzled, wave-private slices

    const int tid  = threadIdx.x;
    const int lane = tid & 63;
    const int wv   = tid >> 6;
    const int lr = lane & 15, lg = lane >> 4;
    const int bh = blockIdx.y, chunk = blockIdx.x;
    const int n_base = chunk * (N_ / CH2);
    const int NT = (N_ / CH2) / 64;   // 8 tiles

    // staging lane geometry (lane-constant): row-in-issue = lane>>3, phys blk = lane&7,
    // logical 8-elem block db = (lane&7) ^ (lane>>3)   [row&7 == lane>>3 for all issues]
    const int srw = lane >> 3;
    const int sdb = (lane & 7) ^ srw;
    const _Float16* gK = kh  + ((size_t)bh * N_ + wv * 16 + srw) * DH + sdb * 8;   // + n*DH
    const _Float16* gV = vTh + ((size_t)bh * DH + wv * 16 + srw) * N_ + sdb * 8;   // + n
    const int ldsR0 = (wv * 16) * 128;   // byte offset of this wave's issue-0 rows

    half8 bfP[4][2];
#pragma unroll
    for (int j = 0; j < 4; ++j)
#pragma unroll
        for (int ks = 0; ks < 2; ++ks)
            bfP[j][ks] = *(const half8*)(projh + (size_t)(64 * wv + 16 * j + lr) * DH + 32 * ks + 8 * lg);

    floatx4 cacc[4][4] = {};
    float ks_acc[4] = {0.f, 0.f, 0.f, 0.f};

    // stage tile 0 into buffer 0
    {
        const size_t n0 = n_base;
        GLD_LDS16(gK + n0 * DH,             (char*)Kt[0] + ldsR0);
        GLD_LDS16(gK + (n0 + 8) * DH,       (char*)Kt[0] + ldsR0 + 8 * 128);
        GLD_LDS16(gV + n0,                  (char*)Vt[0] + ldsR0);
        GLD_LDS16(gV + n0 + 8 * (size_t)N_, (char*)Vt[0] + ldsR0 + 8 * 128);
    }

    for (int t = 0; t < NT; ++t) {
        __syncthreads();   // drains vmcnt -> tile t staged; all waves done with buf (t+1)&1
        if (t + 1 < NT) {
            const size_t n1 = n_base + (size_t)(t + 1) * 64;
            const int b = (t + 1) & 1;
            GLD_LDS16(gK + n1 * DH,             (char*)Kt[b] + ldsR0);
            GLD_LDS16(gK + (n1 + 8) * DH,       (char*)Kt[b] + ldsR0 + 8 * 128);
            GLD_LDS16(gV + n1,                  (char*)Vt[b] + ldsR0);
            GLD_LDS16(gV + n1 + 8 * (size_t)N_, (char*)Vt[b] + ldsR0 + 8 * 128);
        }
        const _Float16* KtB = Kt[t & 1];
        const _Float16* VtB = Vt[t & 1];

        floatx4 s[4][4] = {};
#pragma unroll
        for (int ks = 0; ks < 2; ++ks) {
            half8 aK[4];
#pragma unroll
            for (int i = 0; i < 4; ++i) {
                const int r = 16 * i + lr;
                aK[i] = *(const half8*)((const char*)KtB + r * 128 + (((4 * ks + lg) ^ (r & 7)) * 16));
            }
#pragma unroll
            for (int i = 0; i < 4; ++i)
#pragma unroll
                for (int j = 0; j < 4; ++j)
                    s[i][j] = __builtin_amdgcn_mfma_f32_16x16x32_f16(aK[i], bfP[j][ks], s[i][j], 0, 0, 0);
        }
#pragma unroll
        for (int i = 0; i < 4; ++i)
#pragma unroll
            for (int j = 0; j < 4; ++j) {
                const int m = 64 * wv + 16 * j + lr;
                const int nn0 = 16 * i + 4 * lg;
                half4v h4;
#pragma unroll
                for (int rg = 0; rg < 4; ++rg) {
                    const float kv = fmaxf(s[i][j][rg], 0.f) + EPS;
                    ks_acc[j] += kv;
                    h4[rg] = (_Float16)kv;
                }
                const int db = nn0 >> 3, sub = nn0 & 7;
                *(half4v*)((char*)Sp + m * 128 + ((db ^ (m & 7)) * 16) + sub * 2) = h4;
            }
#pragma unroll
        for (int ks = 0; ks < 2; ++ks) {
            half8 aV[4], bS[4];
#pragma unroll
            for (int i = 0; i < 4; ++i) {
                const int r = 16 * i + lr;
                aV[i] = *(const half8*)((const char*)VtB + r * 128 + (((4 * ks + lg) ^ (r & 7)) * 16));
            }
#pragma unroll
            for (int j = 0; j < 4; ++j) {
                const int m = 64 * wv + 16 * j + lr;
                bS[j] = *(const half8*)((const char*)Sp + m * 128 + (((4 * ks + lg) ^ (m & 7)) * 16));
            }
#pragma unroll
            for (int i = 0; i < 4; ++i)
#pragma unroll
                for (int j = 0; j < 4; ++j)
                    cacc[i][j] = __builtin_amdgcn_mfma_f32_16x16x32_f16(aV[i], bS[j], cacc[i][j], 0, 0, 0);
        }
    }

#pragma unroll
    for (int i = 0; i < 4; ++i)
#pragma unroll
        for (int j = 0; j < 4; ++j)
#pragma unroll
            for (int rg = 0; rg < 4; ++rg) {
                const int d = 16 * i + 4 * lg + rg;
                const int m = 64 * wv + 16 * j + lr;
                ctx_part[(((size_t)chunk * BH + bh) * DH + d) * M_ + m] = cacc[i][j][rg];
            }
#pragma unroll
    for (int j = 0; j < 4; ++j) {
        float v = ks_acc[j];
        v += __shfl_xor(v, 16);
        v += __shfl_xor(v, 32);
        if (lg == 0)
            ksum_part[((size_t)chunk * BH + bh) * M_ + 64 * wv + 16 * j + lr] = v;
    }
}

// ---------- reduce partials -> ctxTh f16 [bh][d][m], ksumh f16 [bh][m] ----------
__global__ __launch_bounds__(256) void reduce_ctx(
    const float* __restrict__ ctx_part, const float* __restrict__ ksum_part,
    _Float16* __restrict__ ctxTh, _Float16* __restrict__ ksumh)
{
    const int idx = blockIdx.x * 256 + threadIdx.x;
    const int CTX = BH * DH * M_;
    if (idx < CTX) {
        float sum = 0.f;
#pragma unroll
        for (int c = 0; c < CH2; ++c) sum += ctx_part[(size_t)c * CTX + idx];
        ctxTh[idx] = (_Float16)sum;
    } else {
        const int kidx = idx - CTX;
        if (kidx < BH * M_) {
            float sum = 0.f;
#pragma unroll
            for (int c = 0; c < CH2; ++c) sum += ksum_part[(size_t)c * BH * M_ + kidx];
            ksumh[kidx] = (_Float16)sum;
        }
    }
}

// ---------- Phase 3: out[n][d] = (q' ctx) / (q'.ksum) ----------
__global__ __launch_bounds__(256) void attn_out_mfma(
    const _Float16* __restrict__ qh, const _Float16* __restrict__ projh,
    const _Float16* __restrict__ ctxTh, const _Float16* __restrict__ ksumh,
    float* __restrict__ out)
{
    __shared__ __align__(16) _Float16 Sp[64 * 256];

    const int tid  = threadIdx.x;
    const int lane = tid & 63;
    const int wv   = tid >> 6;
    const int lr = lane & 15, lg = lane >> 4;
    const int bh = blockIdx.y;
    const int bi = bh >> 4, h = bh & 15;
    const int n_base = blockIdx.x * (N_ / CH3);

    half8 afP[4][2];
#pragma unroll
    for (int I = 0; I < 4; ++I)
#pragma unroll
        for (int ks = 0; ks < 2; ++ks)
            afP[I][ks] = *(const half8*)(projh + (size_t)(64 * wv + 16 * I + lr) * DH + 32 * ks + 8 * lg);

    for (int t = 0; t < (N_ / CH3) / 64; ++t) {
        const int n0 = n_base + t * 64;
        __syncthreads();
        floatx4 sacc[4][4] = {};
#pragma unroll
        for (int ks = 0; ks < 2; ++ks) {
            half8 bq[4];
#pragma unroll
            for (int J = 0; J < 4; ++J)
                bq[J] = *(const half8*)(qh + ((size_t)bh * N_ + n0 + 16 * J + lr) * DH + 32 * ks + 8 * lg);
#pragma unroll
            for (int I = 0; I < 4; ++I)
#pragma unroll
                for (int J = 0; J < 4; ++J)
                    sacc[I][J] = __builtin_amdgcn_mfma_f32_16x16x32_f16(afP[I][ks], bq[J], sacc[I][J], 0, 0, 0);
        }
#pragma unroll
        for (int I = 0; I < 4; ++I)
#pragma unroll
            for (int J = 0; J < 4; ++J) {
                const int n = 16 * J + lr;
                const int m0 = 64 * wv + 16 * I + 4 * lg;
                half4v h4;
#pragma unroll
                for (int rg = 0; rg < 4; ++rg)
                    h4[rg] = (_Float16)(fmaxf(sacc[I][J][rg], 0.f) + EPS);
                const int db = m0 >> 3, sub = m0 & 7;
                *(half4v*)((char*)Sp + n * 512 + ((db ^ (n & 31)) * 16) + sub * 2) = h4;
            }
        __syncthreads();
        floatx4 oacc[4] = {};
        floatx4 dacc = {};
        const int nl = 16 * wv + lr;
#pragma unroll
        for (int ks = 0; ks < 8; ++ks) {
            half8 aq = *(const half8*)((const char*)Sp + nl * 512 + (((4 * ks + lg) ^ (nl & 31)) * 16));
#pragma unroll
            for (int j = 0; j < 4; ++j) {
                half8 bc = *(const half8*)(ctxTh + ((size_t)bh * DH + 16 * j + lr) * M_ + 32 * ks + 8 * lg);
                oacc[j] = __builtin_amdgcn_mfma_f32_16x16x32_f16(aq, bc, oacc[j], 0, 0, 0);
            }
            half8 bk = {};
            if (lr == 0)
                bk = *(const half8*)(ksumh + (size_t)bh * M_ + 32 * ks + 8 * lg);
            dacc = __builtin_amdgcn_mfma_f32_16x16x32_f16(aq, bk, dacc, 0, 0, 0);
        }
#pragma unroll
        for (int rg = 0; rg < 4; ++rg) {
            float den = dacc[rg];
            den = __shfl(den, lane & 48);
            const float dinv = 1.f / den;
            const int n = n0 + 16 * wv + 4 * lg + rg;
#pragma unroll
            for (int j = 0; j < 4; ++j)
                out[(((size_t)bi * N_ + n) * NH + h) * DH + 16 * j + lr] = oacc[j][rg] * dinv;
        }
    }
}

extern "C" void kernel_launch(void* const* d_in, const int* in_sizes, int n_in,
                              void* d_out, int out_size, void* d_ws, size_t ws_size,
                              hipStream_t stream) {
    const float* x    = (const float*)d_in[0];
    const float* w    = (const float*)d_in[1];
    const float* bias = (const float*)d_in[2];
    const float* proj = (const float*)d_in[3];
    float* out = (float*)d_out;
    char* ws = (char*)d_ws;

    const size_t XN  = (size_t)B_ * N_ * HID;  // 16,777,216
    const size_t QKV = (size_t)BH * N_ * DH;   // 16,777,216
    const size_t CTX = (size_t)BH * DH * M_;   // 1,048,576

    _Float16* xh       = (_Float16*)ws;                          ws += XN * 2;
    _Float16* wT       = (_Float16*)ws;                          ws += NC3 * HID * 2;
    _Float16* projh    = (_Float16*)ws;                          ws += M_ * DH * 2;
    _Float16* qh       = (_Float16*)ws;                          ws += QKV * 2;
    _Float16* kh       = (_Float16*)ws;                          ws += QKV * 2;
    _Float16* vTh      = (_Float16*)ws;                          ws += QKV * 2;
    _Float16* ctxTh    = (_Float16*)ws;                          ws += CTX * 2;
    _Float16* ksumh    = (_Float16*)ws;                          ws += BH * M_ * 2;
    float*    ctx_part = (float*)ws;                             ws += (size_t)CH2 * CTX * 4;
    float*    ksum_part= (float*)ws;                             ws += (size_t)CH2 * BH * M_ * 4;

    convert_xh<<<dim3(XN / (256 * 8)), 256, 0, stream>>>(x, xh);
    convert_wT<<<dim3(NC3 / 64, HID / 64), 256, 0, stream>>>(w, wT);
    convert_projh<<<dim3(M_ * DH / 256), 256, 0, stream>>>(proj, projh);

    gemm_qkv_mfma<<<dim3(768), dim3(512), 0, stream>>>(xh, wT, bias, qh, kh, vTh);

    kv_ctx_mfma<<<dim3(CH2, BH), 256, 0, stream>>>(kh, vTh, projh, ctx_part, ksum_part);

    reduce_ctx<<<dim3((CTX + BH * M_ + 255) / 256), 256, 0, stream>>>(ctx_part, ksum_part, ctxTh, ksumh);

    attn_out_mfma<<<dim3(CH3, BH), 256, 0, stream>>>(qh, projh, ctxTh, ksumh, out);
}

// Round 6
// 341.630 us; speedup vs baseline: 1.0900x; 1.0900x over previous
//
#include <hip/hip_runtime.h>

#define B_   4
#define N_   4096
#define NH   16
#define DH   64
#define HID  1024
#define NC3  3072
#define M_   256
#define BH   64
#define SCALE 0.125f
#define EPS   1e-3f
#define CH2  8
#define CH3  16

typedef _Float16 half8  __attribute__((ext_vector_type(8)));
typedef _Float16 half4v __attribute__((ext_vector_type(4)));
typedef float floatx4   __attribute__((ext_vector_type(4)));

#define GLD_LDS16(gptr, lds_base) \
  __builtin_amdgcn_global_load_lds((const __attribute__((address_space(1))) void*)(gptr), \
                                   (__attribute__((address_space(3))) void*)(lds_base), 16, 0, 0)

// barrier that is also a compiler memory fence (no sched_barrier pinning)
#define SBAR() asm volatile("s_barrier" ::: "memory")

// ---------- xh = (f16) x ; tail blocks convert proj ----------
__global__ __launch_bounds__(256) void convert_xh(
    const float* __restrict__ x, _Float16* __restrict__ xh,
    const float* __restrict__ proj, _Float16* __restrict__ projh)
{
    if (blockIdx.x >= 8192) {            // proj tail: 64 blocks cover 16384 elems
        const int i = (blockIdx.x - 8192) * 256 + threadIdx.x;
        projh[i] = (_Float16)proj[i];
        return;
    }
    const size_t i = ((size_t)blockIdx.x * 256 + threadIdx.x) * 8;
    float4 a = *(const float4*)(x + i);
    float4 b = *(const float4*)(x + i + 4);
    half8 h;
    h[0] = (_Float16)a.x; h[1] = (_Float16)a.y; h[2] = (_Float16)a.z; h[3] = (_Float16)a.w;
    h[4] = (_Float16)b.x; h[5] = (_Float16)b.y; h[6] = (_Float16)b.z; h[7] = (_Float16)b.w;
    *(half8*)(xh + i) = h;
}

// ---------- wT[n][k] = (f16) w[k][n]  (q/k bands pre-scaled by d^-0.25) ----------
__global__ __launch_bounds__(256) void convert_wT(
    const float* __restrict__ w, _Float16* __restrict__ wT)
{
    __shared__ float t[64][65];
    const int tid = threadIdx.x;
    const int kb = blockIdx.y * 64, nb = blockIdx.x * 64;
    const int c = tid & 63, r0 = tid >> 6;
#pragma unroll
    for (int rr = 0; rr < 64; rr += 4)
        t[rr + r0][c] = w[(size_t)(kb + rr + r0) * NC3 + nb + c];
    __syncthreads();
    const float sc = (nb < 2048) ? SCALE : 1.0f;   // band is 64-wide: uniform per block
#pragma unroll
    for (int rr = 0; rr < 64; rr += 4)
        wT[(size_t)(nb + rr + r0) * HID + kb + c] = (_Float16)(t[c][rr + r0] * sc);
}

// ---------- Phase 1: qkv GEMM, 256x256 tile, BK=64, 8-wave, 2-barrier/tile pipeline ----------
// (round-2 verified K-loop: best measured 122-125 us)
// Epilogue: q/k blocks bounce acc through wave-private 16KB LDS slabs (XOR-swizzled)
// so global stores are 16B/lane fully coalesced (fixes 32B-segment sector RMW).
__device__ __forceinline__ void stage_tile_qkv(
    const _Float16* __restrict__ xh, const _Float16* __restrict__ wT,
    int row0, int col0, int kt, char* ab, char* bb, int wv, int srow, int sblk)
{
    const size_t ko = (size_t)kt * 64;
#pragma unroll
    for (int s = 0; s < 4; ++s) {
        const int r = s * 64 + srow;
        GLD_LDS16(xh + (size_t)(row0 + r) * HID + ko + 8 * sblk, ab + s * 8192 + wv * 1024);
        GLD_LDS16(wT + (size_t)(col0 + r) * HID + ko + 8 * sblk, bb + s * 8192 + wv * 1024);
    }
}

__global__ __launch_bounds__(512, 2) void gemm_qkv_mfma(
    const _Float16* __restrict__ xh, const _Float16* __restrict__ wT,
    const float* __restrict__ bias,
    _Float16* __restrict__ qh, _Float16* __restrict__ kh, _Float16* __restrict__ vTh)
{
    __shared__ __align__(16) char smem[131072];

    const int tid  = threadIdx.x;
    const int lane = tid & 63;
    const int wv   = tid >> 6;       // 0..7
    const int wm   = wv >> 2;        // 0..1  -> rows wm*128..+128
    const int wn   = wv & 3;         // 0..3  -> cols wn*64..+64
    const int lr   = lane & 15;
    const int lg   = lane >> 4;
    const int lr7  = lr & 7;

    // XCD-aware bijective swizzle: 768 tiles, 8 XCDs, 96 tiles per XCD chunk
    const int bid  = blockIdx.x;
    const int tile = ((bid & 7) * 96) + (bid >> 3);
    const int tm   = tile / 12;
    const int tn   = tile - tm * 12;
    const int row0 = tm * 256;
    const int col0 = tn * 256;

    // staging geometry: per issue (8192 B), wave wv covers 8 rows; lane -> (row, phys blk)
    const int srow = 8 * wv + (lane >> 3);
    const int sblk = (lane & 7) ^ (lane >> 3);   // logical block for linear phys slot (lane&7)

    char* buf0A = smem;
    char* buf0B = smem + 32768;
    char* buf1A = smem + 65536;
    char* buf1B = smem + 98304;

    floatx4 acc[8][4] = {};

    // prologue: tiles 0 and 1 in flight (16 loads per wave)
    stage_tile_qkv(xh, wT, row0, col0, 0, buf0A, buf0B, wv, srow, sblk);
    stage_tile_qkv(xh, wT, row0, col0, 1, buf1A, buf1B, wv, srow, sblk);

    for (int t = 0; t < 16; ++t) {
        // counted vmcnt: tile t's 8 loads landed; next tile's 8 stay in flight
        if (t < 15) asm volatile("s_waitcnt vmcnt(8)" ::: "memory");
        else        asm volatile("s_waitcnt vmcnt(0)" ::: "memory");
        SBAR();

        char* ab = (t & 1) ? buf1A : buf0A;
        char* bb = (t & 1) ? buf1B : buf0B;

        // ---- fragments, K-half 0 (k 0..31) ----
        half8 a0[8], b0[4];
#pragma unroll
        for (int i = 0; i < 8; ++i)
            a0[i] = *(const half8*)(ab + (wm * 128 + 16 * i + lr) * 128 + ((lg ^ lr7) * 16));
#pragma unroll
        for (int j = 0; j < 4; ++j)
            b0[j] = *(const half8*)(bb + (wn * 64 + 16 * j + lr) * 128 + ((lg ^ lr7) * 16));

        __builtin_amdgcn_s_setprio(1);
#pragma unroll
        for (int i = 0; i < 8; ++i)
#pragma unroll
            for (int j = 0; j < 4; ++j)
                acc[i][j] = __builtin_amdgcn_mfma_f32_16x16x32_f16(a0[i], b0[j], acc[i][j], 0, 0, 0);
        __builtin_amdgcn_s_setprio(0);

        // ---- fragments, K-half 1 (k 32..63) ----
        half8 a1[8], b1[4];
#pragma unroll
        for (int i = 0; i < 8; ++i)
            a1[i] = *(const half8*)(ab + (wm * 128 + 16 * i + lr) * 128 + (((4 + lg) ^ lr7) * 16));
#pragma unroll
        for (int j = 0; j < 4; ++j)
            b1[j] = *(const half8*)(bb + (wn * 64 + 16 * j + lr) * 128 + (((4 + lg) ^ lr7) * 16));

        // this wave's LDS reads of buf[t&1] complete -> all waves done -> buffer is free
        asm volatile("s_waitcnt lgkmcnt(0)" ::: "memory");
        SBAR();
        if (t < 14)
            stage_tile_qkv(xh, wT, row0, col0, t + 2, ab, bb, wv, srow, sblk);

        __builtin_amdgcn_s_setprio(1);
#pragma unroll
        for (int i = 0; i < 8; ++i)
#pragma unroll
            for (int j = 0; j < 4; ++j)
                acc[i][j] = __builtin_amdgcn_mfma_f32_16x16x32_f16(a1[i], b1[j], acc[i][j], 0, 0, 0);
        __builtin_amdgcn_s_setprio(0);
    }

    // ---- epilogue ----
    // which is block-uniform: col0 is 256-aligned, so [col0, col0+256) lies in one of q/k/v.
    const int which = col0 >> 10;
    if (which == 2) {
        // v path (unchanged): half4v stores assemble full lines across i in L2
#pragma unroll
        for (int j = 0; j < 4; ++j) {
            const int col = col0 + wn * 64 + 16 * j + lr;
            const int h = (col >> 6) & 15;
            const int d = col & 63;
            const float bb2 = bias[col];
#pragma unroll
            for (int i = 0; i < 8; ++i) {
                const int m0 = row0 + wm * 128 + 16 * i + 4 * lg;
                const int bi = m0 >> 12, n0 = m0 & (N_ - 1);
                half4v hv;
#pragma unroll
                for (int rg = 0; rg < 4; ++rg) hv[rg] = (_Float16)(acc[i][j][rg] + bb2);
                *(half4v*)(vTh + ((size_t)(bi * NH + h) * DH + d) * N_ + n0) = hv;
            }
        }
    } else {
        // q/k path: LDS transpose in wave-private 16KB slab, then coalesced 16B stores.
        // Post-K-loop smem reuse is race-free: every wave passed the t=15 mid-barrier
        // after lgkmcnt(0), so all LDS reads (all waves) are retired.
        _Float16* dst = (which == 0) ? qh : kh;
        const int h = ((col0 + wn * 64) >> 6) & 15;
        char* slab = smem + wv * 16384;   // [128 n][64 d] f16, phys_blk = (d>>3) ^ (n&7)
#pragma unroll
        for (int i = 0; i < 8; ++i)
#pragma unroll
            for (int j = 0; j < 4; ++j) {
                const float bb2 = bias[col0 + wn * 64 + 16 * j + lr] * SCALE;
                const int d  = 16 * j + lr;
#pragma unroll
                for (int rg = 0; rg < 4; ++rg) {
                    const int nl = 16 * i + 4 * lg + rg;
                    const int pb = (d >> 3) ^ (nl & 7);
                    *(_Float16*)(slab + nl * 128 + pb * 16 + (d & 7) * 2) =
                        (_Float16)(acc[i][j][rg] + bb2);
                }
            }
        // read rows back: lane (r = lane>>3, c = lane&7) reads logical d-block c of row
        // nl = it*8 + r  (phys = c ^ (nl&7)  ->  logical = c, conflict-free per 8-lane group)
#pragma unroll
        for (int it = 0; it < 16; ++it) {
            const int nl = it * 8 + (lane >> 3);
            const int pb = (lane & 7) ^ (nl & 7);
            half8 v8 = *(const half8*)(slab + nl * 128 + pb * 16);
            const int m = row0 + wm * 128 + nl;
            const int bi = m >> 12, n = m & (N_ - 1);
            *(half8*)(dst + ((size_t)(bi * NH + h) * N_ + n) * DH + (lane & 7) * 8) = v8;
        }
    }
}

// ---------- Phase 2: per (chunk,bh): ctxT_part[d][m] = sum_n vT[d][n] * k'[n][m] ----------
// (round-0/2 version verbatim: known-good, 234.7us aggregate baseline)
__global__ __launch_bounds__(256) void kv_ctx_mfma(
    const _Float16* __restrict__ kh, const _Float16* __restrict__ vTh,
    const _Float16* __restrict__ projh,
    float* __restrict__ ctx_part, float* __restrict__ ksum_part)
{
    __shared__ __align__(16) _Float16 Kt[64 * 64];   // [n][d] swizzled
    __shared__ __align__(16) _Float16 Vt[64 * 64];   // [d][n] swizzled
    __shared__ __align__(16) _Float16 Sp[256 * 64];  // [m][n] swizzled, wave-private slices

    const int tid  = threadIdx.x;
    const int lane = tid & 63;
    const int wv   = tid >> 6;
    const int lr = lane & 15, lg = lane >> 4;
    const int bh = blockIdx.y, chunk = blockIdx.x;
    const int n_base = chunk * (N_ / CH2);

    half8 bfP[4][2];
#pragma unroll
    for (int j = 0; j < 4; ++j)
#pragma unroll
        for (int ks = 0; ks < 2; ++ks)
            bfP[j][ks] = *(const half8*)(projh + (size_t)(64 * wv + 16 * j + lr) * DH + 32 * ks + 8 * lg);

    floatx4 cacc[4][4] = {};
    float ks_acc[4] = {0.f, 0.f, 0.f, 0.f};

    for (int t = 0; t < (N_ / CH2) / 64; ++t) {
        const int n0 = n_base + t * 64;
        __syncthreads();
#pragma unroll
        for (int s = 0; s < 2; ++s) {
            const int R = wv * 16 + s * 8;
            const int r = R + (lane >> 3);
            const int db = (lane & 7) ^ (r & 7);
            GLD_LDS16(kh + ((size_t)(bh * N_ + n0 + r)) * DH + db * 8, (char*)Kt + R * 128);
        }
#pragma unroll
        for (int s = 0; s < 2; ++s) {
            const int R = wv * 16 + s * 8;
            const int r = R + (lane >> 3);
            const int db = (lane & 7) ^ (r & 7);
            GLD_LDS16(vTh + ((size_t)(bh * DH + r)) * N_ + n0 + db * 8, (char*)Vt + R * 128);
        }
        __syncthreads();

        floatx4 s[4][4] = {};
#pragma unroll
        for (int ks = 0; ks < 2; ++ks) {
            half8 aK[4];
#pragma unroll
            for (int i = 0; i < 4; ++i) {
                const int r = 16 * i + lr;
                aK[i] = *(const half8*)((const char*)Kt + r * 128 + (((4 * ks + lg) ^ (r & 7)) * 16));
            }
#pragma unroll
            for (int i = 0; i < 4; ++i)
#pragma unroll
                for (int j = 0; j < 4; ++j)
                    s[i][j] = __builtin_amdgcn_mfma_f32_16x16x32_f16(aK[i], bfP[j][ks], s[i][j], 0, 0, 0);
        }
#pragma unroll
        for (int i = 0; i < 4; ++i)
#pragma unroll
            for (int j = 0; j < 4; ++j) {
                const int m = 64 * wv + 16 * j + lr;
                const int nn0 = 16 * i + 4 * lg;
                half4v h4;
#pragma unroll
                for (int rg = 0; rg < 4; ++rg) {
                    const float kv = fmaxf(s[i][j][rg], 0.f) + EPS;
                    ks_acc[j] += kv;
                    h4[rg] = (_Float16)kv;
                }
                const int db = nn0 >> 3, sub = nn0 & 7;
                *(half4v*)((char*)Sp + m * 128 + ((db ^ (m & 7)) * 16) + sub * 2) = h4;
            }
#pragma unroll
        for (int ks = 0; ks < 2; ++ks) {
            half8 aV[4], bS[4];
#pragma unroll
            for (int i = 0; i < 4; ++i) {
                const int r = 16 * i + lr;
                aV[i] = *(const half8*)((const char*)Vt + r * 128 + (((4 * ks + lg) ^ (r & 7)) * 16));
            }
#pragma unroll
            for (int j = 0; j < 4; ++j) {
                const int m = 64 * wv + 16 * j + lr;
                bS[j] = *(const half8*)((const char*)Sp + m * 128 + (((4 * ks + lg) ^ (m & 7)) * 16));
            }
#pragma unroll
            for (int i = 0; i < 4; ++i)
#pragma unroll
                for (int j = 0; j < 4; ++j)
                    cacc[i][j] = __builtin_amdgcn_mfma_f32_16x16x32_f16(aV[i], bS[j], cacc[i][j], 0, 0, 0);
        }
    }

#pragma unroll
    for (int i = 0; i < 4; ++i)
#pragma unroll
        for (int j = 0; j < 4; ++j)
#pragma unroll
            for (int rg = 0; rg < 4; ++rg) {
                const int d = 16 * i + 4 * lg + rg;
                const int m = 64 * wv + 16 * j + lr;
                ctx_part[(((size_t)chunk * BH + bh) * DH + d) * M_ + m] = cacc[i][j][rg];
            }
#pragma unroll
    for (int j = 0; j < 4; ++j) {
        float v = ks_acc[j];
        v += __shfl_xor(v, 16);
        v += __shfl_xor(v, 32);
        if (lg == 0)
            ksum_part[((size_t)chunk * BH + bh) * M_ + 64 * wv + 16 * j + lr] = v;
    }
}

// ---------- reduce partials -> ctxTh f16 [bh][d][m], ksumh f16 [bh][m] ----------
__global__ __launch_bounds__(256) void reduce_ctx(
    const float* __restrict__ ctx_part, const float* __restrict__ ksum_part,
    _Float16* __restrict__ ctxTh, _Float16* __restrict__ ksumh)
{
    const int idx = blockIdx.x * 256 + threadIdx.x;
    const int CTX = BH * DH * M_;
    if (idx < CTX) {
        float sum = 0.f;
#pragma unroll
        for (int c = 0; c < CH2; ++c) sum += ctx_part[(size_t)c * CTX + idx];
        ctxTh[idx] = (_Float16)sum;
    } else {
        const int kidx = idx - CTX;
        if (kidx < BH * M_) {
            float sum = 0.f;
#pragma unroll
            for (int c = 0; c < CH2; ++c) sum += ksum_part[(size_t)c * BH * M_ + kidx];
            ksumh[kidx] = (_Float16)sum;
        }
    }
}

// ---------- Phase 3: out[n][d] = (q' ctx) / (q'.ksum) ----------
__global__ __launch_bounds__(256) void attn_out_mfma(
    const _Float16* __restrict__ qh, const _Float16* __restrict__ projh,
    const _Float16* __restrict__ ctxTh, const _Float16* __restrict__ ksumh,
    float* __restrict__ out)
{
    __shared__ __align__(16) _Float16 Sp[64 * 256];

    const int tid  = threadIdx.x;
    const int lane = tid & 63;
    const int wv   = tid >> 6;
    const int lr = lane & 15, lg = lane >> 4;
    const int bh = blockIdx.y;
    const int bi = bh >> 4, h = bh & 15;
    const int n_base = blockIdx.x * (N_ / CH3);

    half8 afP[4][2];
#pragma unroll
    for (int I = 0; I < 4; ++I)
#pragma unroll
        for (int ks = 0; ks < 2; ++ks)
            afP[I][ks] = *(const half8*)(projh + (size_t)(64 * wv + 16 * I + lr) * DH + 32 * ks + 8 * lg);

    for (int t = 0; t < (N_ / CH3) / 64; ++t) {
        const int n0 = n_base + t * 64;
        __syncthreads();
        floatx4 sacc[4][4] = {};
#pragma unroll
        for (int ks = 0; ks < 2; ++ks) {
            half8 bq[4];
#pragma unroll
            for (int J = 0; J < 4; ++J)
                bq[J] = *(const half8*)(qh + ((size_t)bh * N_ + n0 + 16 * J + lr) * DH + 32 * ks + 8 * lg);
#pragma unroll
            for (int I = 0; I < 4; ++I)
#pragma unroll
                for (int J = 0; J < 4; ++J)
                    sacc[I][J] = __builtin_amdgcn_mfma_f32_16x16x32_f16(afP[I][ks], bq[J], sacc[I][J], 0, 0, 0);
        }
#pragma unroll
        for (int I = 0; I < 4; ++I)
#pragma unroll
            for (int J = 0; J < 4; ++J) {
                const int n = 16 * J + lr;
                const int m0 = 64 * wv + 16 * I + 4 * lg;
                half4v h4;
#pragma unroll
                for (int rg = 0; rg < 4; ++rg)
                    h4[rg] = (_Float16)(fmaxf(sacc[I][J][rg], 0.f) + EPS);
                const int db = m0 >> 3, sub = m0 & 7;
                *(half4v*)((char*)Sp + n * 512 + ((db ^ (n & 31)) * 16) + sub * 2) = h4;
            }
        __syncthreads();
        floatx4 oacc[4] = {};
        floatx4 dacc = {};
        const int nl = 16 * wv + lr;
#pragma unroll
        for (int ks = 0; ks < 8; ++ks) {
            half8 aq = *(const half8*)((const char*)Sp + nl * 512 + (((4 * ks + lg) ^ (nl & 31)) * 16));
#pragma unroll
            for (int j = 0; j < 4; ++j) {
                half8 bc = *(const half8*)(ctxTh + ((size_t)bh * DH + 16 * j + lr) * M_ + 32 * ks + 8 * lg);
                oacc[j] = __builtin_amdgcn_mfma_f32_16x16x32_f16(aq, bc, oacc[j], 0, 0, 0);
            }
            half8 bk = {};
            if (lr == 0)
                bk = *(const half8*)(ksumh + (size_t)bh * M_ + 32 * ks + 8 * lg);
            dacc = __builtin_amdgcn_mfma_f32_16x16x32_f16(aq, bk, dacc, 0, 0, 0);
        }
#pragma unroll
        for (int rg = 0; rg < 4; ++rg) {
            float den = dacc[rg];
            den = __shfl(den, lane & 48);
            const float dinv = 1.f / den;
            const int n = n0 + 16 * wv + 4 * lg + rg;
#pragma unroll
            for (int j = 0; j < 4; ++j)
                out[(((size_t)bi * N_ + n) * NH + h) * DH + 16 * j + lr] = oacc[j][rg] * dinv;
        }
    }
}

extern "C" void kernel_launch(void* const* d_in, const int* in_sizes, int n_in,
                              void* d_out, int out_size, void* d_ws, size_t ws_size,
                              hipStream_t stream) {
    const float* x    = (const float*)d_in[0];
    const float* w    = (const float*)d_in[1];
    const float* bias = (const float*)d_in[2];
    const float* proj = (const float*)d_in[3];
    float* out = (float*)d_out;
    char* ws = (char*)d_ws;

    const size_t XN  = (size_t)B_ * N_ * HID;  // 16,777,216
    const size_t QKV = (size_t)BH * N_ * DH;   // 16,777,216
    const size_t CTX = (size_t)BH * DH * M_;   // 1,048,576

    _Float16* xh       = (_Float16*)ws;                          ws += XN * 2;
    _Float16* wT       = (_Float16*)ws;                          ws += NC3 * HID * 2;
    _Float16* projh    = (_Float16*)ws;                          ws += M_ * DH * 2;
    _Float16* qh       = (_Float16*)ws;                          ws += QKV * 2;
    _Float16* kh       = (_Float16*)ws;                          ws += QKV * 2;
    _Float16* vTh      = (_Float16*)ws;                          ws += QKV * 2;
    _Float16* ctxTh    = (_Float16*)ws;                          ws += CTX * 2;
    _Float16* ksumh    = (_Float16*)ws;                          ws += BH * M_ * 2;
    float*    ctx_part = (float*)ws;                             ws += (size_t)CH2 * CTX * 4;
    float*    ksum_part= (float*)ws;                             ws += (size_t)CH2 * BH * M_ * 4;

    convert_xh<<<dim3(XN / (256 * 8) + 64), 256, 0, stream>>>(x, xh, proj, projh);
    convert_wT<<<dim3(NC3 / 64, HID / 64), 256, 0, stream>>>(w, wT);

    gemm_qkv_mfma<<<dim3(768), dim3(512), 0, stream>>>(xh, wT, bias, qh, kh, vTh);

    kv_ctx_mfma<<<dim3(CH2, BH), 256, 0, stream>>>(kh, vTh, projh, ctx_part, ksum_part);

    reduce_ctx<<<dim3((CTX + BH * M_ + 255) / 256), 256, 0, stream>>>(ctx_part, ksum_part, ctxTh, ksumh);

    attn_out_mfma<<<dim3(CH3, BH), 256, 0, stream>>>(qh, projh, ctxTh, ksumh, out);
}

// Round 7
// 314.895 us; speedup vs baseline: 1.1825x; 1.0849x over previous
//
#include <hip/hip_runtime.h>

#define B_   4
#define N_   4096
#define NH   16
#define DH   64
#define HID  1024
#define NC3  3072
#define M_   256
#define BH   64
#define SCALE 0.125f
#define EPS   1e-3f
#define CH2  8
#define CH3  8

typedef _Float16 half8  __attribute__((ext_vector_type(8)));
typedef _Float16 half4v __attribute__((ext_vector_type(4)));
typedef float floatx4   __attribute__((ext_vector_type(4)));

#define GLD_LDS16(gptr, lds_base) \
  __builtin_amdgcn_global_load_lds((const __attribute__((address_space(1))) void*)(gptr), \
                                   (__attribute__((address_space(3))) void*)(lds_base), 16, 0, 0)

// barrier that is also a compiler memory fence (no sched_barrier pinning)
#define SBAR() asm volatile("s_barrier" ::: "memory")

// ---------- xh = (f16) x ; tail blocks convert proj ----------
__global__ __launch_bounds__(256) void convert_xh(
    const float* __restrict__ x, _Float16* __restrict__ xh,
    const float* __restrict__ proj, _Float16* __restrict__ projh)
{
    if (blockIdx.x >= 8192) {            // proj tail: 64 blocks cover 16384 elems
        const int i = (blockIdx.x - 8192) * 256 + threadIdx.x;
        projh[i] = (_Float16)proj[i];
        return;
    }
    const size_t i = ((size_t)blockIdx.x * 256 + threadIdx.x) * 8;
    float4 a = *(const float4*)(x + i);
    float4 b = *(const float4*)(x + i + 4);
    half8 h;
    h[0] = (_Float16)a.x; h[1] = (_Float16)a.y; h[2] = (_Float16)a.z; h[3] = (_Float16)a.w;
    h[4] = (_Float16)b.x; h[5] = (_Float16)b.y; h[6] = (_Float16)b.z; h[7] = (_Float16)b.w;
    *(half8*)(xh + i) = h;
}

// ---------- wT[n][k] = (f16) w[k][n]  (q/k bands pre-scaled by d^-0.25) ----------
__global__ __launch_bounds__(256) void convert_wT(
    const float* __restrict__ w, _Float16* __restrict__ wT)
{
    __shared__ float t[64][65];
    const int tid = threadIdx.x;
    const int kb = blockIdx.y * 64, nb = blockIdx.x * 64;
    const int c = tid & 63, r0 = tid >> 6;
#pragma unroll
    for (int rr = 0; rr < 64; rr += 4)
        t[rr + r0][c] = w[(size_t)(kb + rr + r0) * NC3 + nb + c];
    __syncthreads();
    const float sc = (nb < 2048) ? SCALE : 1.0f;   // band is 64-wide: uniform per block
#pragma unroll
    for (int rr = 0; rr < 64; rr += 4)
        wT[(size_t)(nb + rr + r0) * HID + kb + c] = (_Float16)(t[c][rr + r0] * sc);
}

// ---------- Phase 1: qkv GEMM, 256x256 tile, BK=64, 8-wave, 2-barrier/tile pipeline ----------
// (round-6 verified: 118 us, WRITE_SIZE 99 MB)
__device__ __forceinline__ void stage_tile_qkv(
    const _Float16* __restrict__ xh, const _Float16* __restrict__ wT,
    int row0, int col0, int kt, char* ab, char* bb, int wv, int srow, int sblk)
{
    const size_t ko = (size_t)kt * 64;
#pragma unroll
    for (int s = 0; s < 4; ++s) {
        const int r = s * 64 + srow;
        GLD_LDS16(xh + (size_t)(row0 + r) * HID + ko + 8 * sblk, ab + s * 8192 + wv * 1024);
        GLD_LDS16(wT + (size_t)(col0 + r) * HID + ko + 8 * sblk, bb + s * 8192 + wv * 1024);
    }
}

__global__ __launch_bounds__(512, 2) void gemm_qkv_mfma(
    const _Float16* __restrict__ xh, const _Float16* __restrict__ wT,
    const float* __restrict__ bias,
    _Float16* __restrict__ qh, _Float16* __restrict__ kh, _Float16* __restrict__ vTh)
{
    __shared__ __align__(16) char smem[131072];

    const int tid  = threadIdx.x;
    const int lane = tid & 63;
    const int wv   = tid >> 6;       // 0..7
    const int wm   = wv >> 2;        // 0..1  -> rows wm*128..+128
    const int wn   = wv & 3;         // 0..3  -> cols wn*64..+64
    const int lr   = lane & 15;
    const int lg   = lane >> 4;
    const int lr7  = lr & 7;

    // XCD-aware bijective swizzle: 768 tiles, 8 XCDs, 96 tiles per XCD chunk
    const int bid  = blockIdx.x;
    const int tile = ((bid & 7) * 96) + (bid >> 3);
    const int tm   = tile / 12;
    const int tn   = tile - tm * 12;
    const int row0 = tm * 256;
    const int col0 = tn * 256;

    // staging geometry: per issue (8192 B), wave wv covers 8 rows; lane -> (row, phys blk)
    const int srow = 8 * wv + (lane >> 3);
    const int sblk = (lane & 7) ^ (lane >> 3);   // logical block for linear phys slot (lane&7)

    char* buf0A = smem;
    char* buf0B = smem + 32768;
    char* buf1A = smem + 65536;
    char* buf1B = smem + 98304;

    floatx4 acc[8][4] = {};

    // prologue: tiles 0 and 1 in flight (16 loads per wave)
    stage_tile_qkv(xh, wT, row0, col0, 0, buf0A, buf0B, wv, srow, sblk);
    stage_tile_qkv(xh, wT, row0, col0, 1, buf1A, buf1B, wv, srow, sblk);

    for (int t = 0; t < 16; ++t) {
        // counted vmcnt: tile t's 8 loads landed; next tile's 8 stay in flight
        if (t < 15) asm volatile("s_waitcnt vmcnt(8)" ::: "memory");
        else        asm volatile("s_waitcnt vmcnt(0)" ::: "memory");
        SBAR();

        char* ab = (t & 1) ? buf1A : buf0A;
        char* bb = (t & 1) ? buf1B : buf0B;

        // ---- fragments, K-half 0 (k 0..31) ----
        half8 a0[8], b0[4];
#pragma unroll
        for (int i = 0; i < 8; ++i)
            a0[i] = *(const half8*)(ab + (wm * 128 + 16 * i + lr) * 128 + ((lg ^ lr7) * 16));
#pragma unroll
        for (int j = 0; j < 4; ++j)
            b0[j] = *(const half8*)(bb + (wn * 64 + 16 * j + lr) * 128 + ((lg ^ lr7) * 16));

        __builtin_amdgcn_s_setprio(1);
#pragma unroll
        for (int i = 0; i < 8; ++i)
#pragma unroll
            for (int j = 0; j < 4; ++j)
                acc[i][j] = __builtin_amdgcn_mfma_f32_16x16x32_f16(a0[i], b0[j], acc[i][j], 0, 0, 0);
        __builtin_amdgcn_s_setprio(0);

        // ---- fragments, K-half 1 (k 32..63) ----
        half8 a1[8], b1[4];
#pragma unroll
        for (int i = 0; i < 8; ++i)
            a1[i] = *(const half8*)(ab + (wm * 128 + 16 * i + lr) * 128 + (((4 + lg) ^ lr7) * 16));
#pragma unroll
        for (int j = 0; j < 4; ++j)
            b1[j] = *(const half8*)(bb + (wn * 64 + 16 * j + lr) * 128 + (((4 + lg) ^ lr7) * 16));

        // this wave's LDS reads of buf[t&1] complete -> all waves done -> buffer is free
        asm volatile("s_waitcnt lgkmcnt(0)" ::: "memory");
        SBAR();
        if (t < 14)
            stage_tile_qkv(xh, wT, row0, col0, t + 2, ab, bb, wv, srow, sblk);

        __builtin_amdgcn_s_setprio(1);
#pragma unroll
        for (int i = 0; i < 8; ++i)
#pragma unroll
            for (int j = 0; j < 4; ++j)
                acc[i][j] = __builtin_amdgcn_mfma_f32_16x16x32_f16(a1[i], b1[j], acc[i][j], 0, 0, 0);
        __builtin_amdgcn_s_setprio(0);
    }

    // ---- epilogue ----
    // which is block-uniform: col0 is 256-aligned, so [col0, col0+256) lies in one of q/k/v.
    const int which = col0 >> 10;
    if (which == 2) {
        // v path: half4v stores assemble full lines across i in L2
#pragma unroll
        for (int j = 0; j < 4; ++j) {
            const int col = col0 + wn * 64 + 16 * j + lr;
            const int h = (col >> 6) & 15;
            const int d = col & 63;
            const float bb2 = bias[col];
#pragma unroll
            for (int i = 0; i < 8; ++i) {
                const int m0 = row0 + wm * 128 + 16 * i + 4 * lg;
                const int bi = m0 >> 12, n0 = m0 & (N_ - 1);
                half4v hv;
#pragma unroll
                for (int rg = 0; rg < 4; ++rg) hv[rg] = (_Float16)(acc[i][j][rg] + bb2);
                *(half4v*)(vTh + ((size_t)(bi * NH + h) * DH + d) * N_ + n0) = hv;
            }
        }
    } else {
        // q/k path: LDS transpose in wave-private 16KB slab, then coalesced 16B stores.
        _Float16* dst = (which == 0) ? qh : kh;
        const int h = ((col0 + wn * 64) >> 6) & 15;
        char* slab = smem + wv * 16384;   // [128 n][64 d] f16, phys_blk = (d>>3) ^ (n&7)
#pragma unroll
        for (int i = 0; i < 8; ++i)
#pragma unroll
            for (int j = 0; j < 4; ++j) {
                const float bb2 = bias[col0 + wn * 64 + 16 * j + lr] * SCALE;
                const int d  = 16 * j + lr;
#pragma unroll
                for (int rg = 0; rg < 4; ++rg) {
                    const int nl = 16 * i + 4 * lg + rg;
                    const int pb = (d >> 3) ^ (nl & 7);
                    *(_Float16*)(slab + nl * 128 + pb * 16 + (d & 7) * 2) =
                        (_Float16)(acc[i][j][rg] + bb2);
                }
            }
#pragma unroll
        for (int it = 0; it < 16; ++it) {
            const int nl = it * 8 + (lane >> 3);
            const int pb = (lane & 7) ^ (nl & 7);
            half8 v8 = *(const half8*)(slab + nl * 128 + pb * 16);
            const int m = row0 + wm * 128 + nl;
            const int bi = m >> 12, n = m & (N_ - 1);
            *(half8*)(dst + ((size_t)(bi * NH + h) * N_ + n) * DH + (lane & 7) * 8) = v8;
        }
    }
}

// ---------- Phase 2: per (chunk,bh): ctxT_part[d][m] = sum_n vT[d][n] * k'[n][m] ----------
// (round-0/2 version verbatim: known-good)
__global__ __launch_bounds__(256) void kv_ctx_mfma(
    const _Float16* __restrict__ kh, const _Float16* __restrict__ vTh,
    const _Float16* __restrict__ projh,
    float* __restrict__ ctx_part, float* __restrict__ ksum_part)
{
    __shared__ __align__(16) _Float16 Kt[64 * 64];   // [n][d] swizzled
    __shared__ __align__(16) _Float16 Vt[64 * 64];   // [d][n] swizzled
    __shared__ __align__(16) _Float16 Sp[256 * 64];  // [m][n] swizzled, wave-private slices

    const int tid  = threadIdx.x;
    const int lane = tid & 63;
    const int wv   = tid >> 6;
    const int lr = lane & 15, lg = lane >> 4;
    const int bh = blockIdx.y, chunk = blockIdx.x;
    const int n_base = chunk * (N_ / CH2);

    half8 bfP[4][2];
#pragma unroll
    for (int j = 0; j < 4; ++j)
#pragma unroll
        for (int ks = 0; ks < 2; ++ks)
            bfP[j][ks] = *(const half8*)(projh + (size_t)(64 * wv + 16 * j + lr) * DH + 32 * ks + 8 * lg);

    floatx4 cacc[4][4] = {};
    float ks_acc[4] = {0.f, 0.f, 0.f, 0.f};

    for (int t = 0; t < (N_ / CH2) / 64; ++t) {
        const int n0 = n_base + t * 64;
        __syncthreads();
#pragma unroll
        for (int s = 0; s < 2; ++s) {
            const int R = wv * 16 + s * 8;
            const int r = R + (lane >> 3);
            const int db = (lane & 7) ^ (r & 7);
            GLD_LDS16(kh + ((size_t)(bh * N_ + n0 + r)) * DH + db * 8, (char*)Kt + R * 128);
        }
#pragma unroll
        for (int s = 0; s < 2; ++s) {
            const int R = wv * 16 + s * 8;
            const int r = R + (lane >> 3);
            const int db = (lane & 7) ^ (r & 7);
            GLD_LDS16(vTh + ((size_t)(bh * DH + r)) * N_ + n0 + db * 8, (char*)Vt + R * 128);
        }
        __syncthreads();

        floatx4 s[4][4] = {};
#pragma unroll
        for (int ks = 0; ks < 2; ++ks) {
            half8 aK[4];
#pragma unroll
            for (int i = 0; i < 4; ++i) {
                const int r = 16 * i + lr;
                aK[i] = *(const half8*)((const char*)Kt + r * 128 + (((4 * ks + lg) ^ (r & 7)) * 16));
            }
#pragma unroll
            for (int i = 0; i < 4; ++i)
#pragma unroll
                for (int j = 0; j < 4; ++j)
                    s[i][j] = __builtin_amdgcn_mfma_f32_16x16x32_f16(aK[i], bfP[j][ks], s[i][j], 0, 0, 0);
        }
#pragma unroll
        for (int i = 0; i < 4; ++i)
#pragma unroll
            for (int j = 0; j < 4; ++j) {
                const int m = 64 * wv + 16 * j + lr;
                const int nn0 = 16 * i + 4 * lg;
                half4v h4;
#pragma unroll
                for (int rg = 0; rg < 4; ++rg) {
                    const float kv = fmaxf(s[i][j][rg], 0.f) + EPS;
                    ks_acc[j] += kv;
                    h4[rg] = (_Float16)kv;
                }
                const int db = nn0 >> 3, sub = nn0 & 7;
                *(half4v*)((char*)Sp + m * 128 + ((db ^ (m & 7)) * 16) + sub * 2) = h4;
            }
#pragma unroll
        for (int ks = 0; ks < 2; ++ks) {
            half8 aV[4], bS[4];
#pragma unroll
            for (int i = 0; i < 4; ++i) {
                const int r = 16 * i + lr;
                aV[i] = *(const half8*)((const char*)Vt + r * 128 + (((4 * ks + lg) ^ (r & 7)) * 16));
            }
#pragma unroll
            for (int j = 0; j < 4; ++j) {
                const int m = 64 * wv + 16 * j + lr;
                bS[j] = *(const half8*)((const char*)Sp + m * 128 + (((4 * ks + lg) ^ (m & 7)) * 16));
            }
#pragma unroll
            for (int i = 0; i < 4; ++i)
#pragma unroll
                for (int j = 0; j < 4; ++j)
                    cacc[i][j] = __builtin_amdgcn_mfma_f32_16x16x32_f16(aV[i], bS[j], cacc[i][j], 0, 0, 0);
        }
    }

#pragma unroll
    for (int i = 0; i < 4; ++i)
#pragma unroll
        for (int j = 0; j < 4; ++j)
#pragma unroll
            for (int rg = 0; rg < 4; ++rg) {
                const int d = 16 * i + 4 * lg + rg;
                const int m = 64 * wv + 16 * j + lr;
                ctx_part[(((size_t)chunk * BH + bh) * DH + d) * M_ + m] = cacc[i][j][rg];
            }
#pragma unroll
    for (int j = 0; j < 4; ++j) {
        float v = ks_acc[j];
        v += __shfl_xor(v, 16);
        v += __shfl_xor(v, 32);
        if (lg == 0)
            ksum_part[((size_t)chunk * BH + bh) * M_ + 64 * wv + 16 * j + lr] = v;
    }
}

// ---------- reduce partials -> ctxTh f16 [bh][d][m], ksumh f16 [bh][m] ----------
__global__ __launch_bounds__(256) void reduce_ctx(
    const float* __restrict__ ctx_part, const float* __restrict__ ksum_part,
    _Float16* __restrict__ ctxTh, _Float16* __restrict__ ksumh)
{
    const int idx = blockIdx.x * 256 + threadIdx.x;
    const int CTX = BH * DH * M_;
    if (idx < CTX) {
        float sum = 0.f;
#pragma unroll
        for (int c = 0; c < CH2; ++c) sum += ctx_part[(size_t)c * CTX + idx];
        ctxTh[idx] = (_Float16)sum;
    } else {
        const int kidx = idx - CTX;
        if (kidx < BH * M_) {
            float sum = 0.f;
#pragma unroll
            for (int c = 0; c < CH2; ++c) sum += ksum_part[(size_t)c * BH * M_ + kidx];
            ksumh[kidx] = (_Float16)sum;
        }
    }
}

// ---------- Phase 3: out[n][d] = (q' ctx) / (q'.ksum) ----------
// ctx staged in LDS once per block (XOR-swizzled source, linear GLD_LDS dest);
// PV reads ctx from LDS instead of re-loading from global every tile.
// CH3=8: 512 blocks, 8 tiles/block; LDS 64 KB -> 2 blocks/CU = grid/CU.
__global__ __launch_bounds__(256) void attn_out_mfma(
    const _Float16* __restrict__ qh, const _Float16* __restrict__ projh,
    const _Float16* __restrict__ ctxTh, const _Float16* __restrict__ ksumh,
    float* __restrict__ out)
{
    __shared__ __align__(16) _Float16 Ct[64 * 256];   // [d][m], phys 16B-blk = logical ^ (d&31)
    __shared__ __align__(16) _Float16 Sp[64 * 256];

    const int tid  = threadIdx.x;
    const int lane = tid & 63;
    const int wv   = tid >> 6;
    const int lr = lane & 15, lg = lane >> 4;
    const int bh = blockIdx.y;
    const int bi = bh >> 4, h = bh & 15;
    const int n_base = blockIdx.x * (N_ / CH3);

    // ---- stage ctx[bh] (32 KB) into Ct: 8 issues x 256 lanes x 16B ----
    // issue s: wave wv covers rows r = s*8 + wv*2 + (lane>>5); phys blk p = lane&31;
    // logical blk lb = p ^ (r&31); dest = Ct + s*4096 + wv*1024 + lane*16 (linear).
    {
        const int r_ = (wv << 1) + (lane >> 5);
        const int p_ = lane & 31;
#pragma unroll
        for (int s = 0; s < 8; ++s) {
            const int r = s * 8 + r_;
            const int lb = p_ ^ (r & 31);
            GLD_LDS16(ctxTh + ((size_t)bh * DH + r) * M_ + lb * 8,
                      (char*)Ct + s * 4096 + wv * 1024);
        }
    }

    half8 afP[4][2];
#pragma unroll
    for (int I = 0; I < 4; ++I)
#pragma unroll
        for (int ks = 0; ks < 2; ++ks)
            afP[I][ks] = *(const half8*)(projh + (size_t)(64 * wv + 16 * I + lr) * DH + 32 * ks + 8 * lg);

    for (int t = 0; t < (N_ / CH3) / 64; ++t) {
        const int n0 = n_base + t * 64;
        __syncthreads();   // first iter: also drains Ct staging (vmcnt 0 at barrier)
        floatx4 sacc[4][4] = {};
#pragma unroll
        for (int ks = 0; ks < 2; ++ks) {
            half8 bq[4];
#pragma unroll
            for (int J = 0; J < 4; ++J)
                bq[J] = *(const half8*)(qh + ((size_t)bh * N_ + n0 + 16 * J + lr) * DH + 32 * ks + 8 * lg);
#pragma unroll
            for (int I = 0; I < 4; ++I)
#pragma unroll
                for (int J = 0; J < 4; ++J)
                    sacc[I][J] = __builtin_amdgcn_mfma_f32_16x16x32_f16(afP[I][ks], bq[J], sacc[I][J], 0, 0, 0);
        }
#pragma unroll
        for (int I = 0; I < 4; ++I)
#pragma unroll
            for (int J = 0; J < 4; ++J) {
                const int n = 16 * J + lr;
                const int m0 = 64 * wv + 16 * I + 4 * lg;
                half4v h4;
#pragma unroll
                for (int rg = 0; rg < 4; ++rg)
                    h4[rg] = (_Float16)(fmaxf(sacc[I][J][rg], 0.f) + EPS);
                const int db = m0 >> 3, sub = m0 & 7;
                *(half4v*)((char*)Sp + n * 512 + ((db ^ (n & 31)) * 16) + sub * 2) = h4;
            }
        __syncthreads();
        floatx4 oacc[4] = {};
        floatx4 dacc = {};
        const int nl = 16 * wv + lr;
#pragma unroll
        for (int ks = 0; ks < 8; ++ks) {
            half8 aq = *(const half8*)((const char*)Sp + nl * 512 + (((4 * ks + lg) ^ (nl & 31)) * 16));
#pragma unroll
            for (int j = 0; j < 4; ++j) {
                const int d = 16 * j + lr;
                const int pb = (4 * ks + lg) ^ (d & 31);
                half8 bc = *(const half8*)((const char*)Ct + d * 512 + pb * 16);
                oacc[j] = __builtin_amdgcn_mfma_f32_16x16x32_f16(aq, bc, oacc[j], 0, 0, 0);
            }
            half8 bk = {};
            if (lr == 0)
                bk = *(const half8*)(ksumh + (size_t)bh * M_ + 32 * ks + 8 * lg);
            dacc = __builtin_amdgcn_mfma_f32_16x16x32_f16(aq, bk, dacc, 0, 0, 0);
        }
#pragma unroll
        for (int rg = 0; rg < 4; ++rg) {
            float den = dacc[rg];
            den = __shfl(den, lane & 48);
            const float dinv = 1.f / den;
            const int n = n0 + 16 * wv + 4 * lg + rg;
#pragma unroll
            for (int j = 0; j < 4; ++j)
                out[(((size_t)bi * N_ + n) * NH + h) * DH + 16 * j + lr] = oacc[j][rg] * dinv;
        }
    }
}

extern "C" void kernel_launch(void* const* d_in, const int* in_sizes, int n_in,
                              void* d_out, int out_size, void* d_ws, size_t ws_size,
                              hipStream_t stream) {
    const float* x    = (const float*)d_in[0];
    const float* w    = (const float*)d_in[1];
    const float* bias = (const float*)d_in[2];
    const float* proj = (const float*)d_in[3];
    float* out = (float*)d_out;
    char* ws = (char*)d_ws;

    const size_t XN  = (size_t)B_ * N_ * HID;  // 16,777,216
    const size_t QKV = (size_t)BH * N_ * DH;   // 16,777,216
    const size_t CTX = (size_t)BH * DH * M_;   // 1,048,576

    _Float16* xh       = (_Float16*)ws;                          ws += XN * 2;
    _Float16* wT       = (_Float16*)ws;                          ws += NC3 * HID * 2;
    _Float16* projh    = (_Float16*)ws;                          ws += M_ * DH * 2;
    _Float16* qh       = (_Float16*)ws;                          ws += QKV * 2;
    _Float16* kh       = (_Float16*)ws;                          ws += QKV * 2;
    _Float16* vTh      = (_Float16*)ws;                          ws += QKV * 2;
    _Float16* ctxTh    = (_Float16*)ws;                          ws += CTX * 2;
    _Float16* ksumh    = (_Float16*)ws;                          ws += BH * M_ * 2;
    float*    ctx_part = (float*)ws;                             ws += (size_t)CH2 * CTX * 4;
    float*    ksum_part= (float*)ws;                             ws += (size_t)CH2 * BH * M_ * 4;

    convert_xh<<<dim3(XN / (256 * 8) + 64), 256, 0, stream>>>(x, xh, proj, projh);
    convert_wT<<<dim3(NC3 / 64, HID / 64), 256, 0, stream>>>(w, wT);

    gemm_qkv_mfma<<<dim3(768), dim3(512), 0, stream>>>(xh, wT, bias, qh, kh, vTh);

    kv_ctx_mfma<<<dim3(CH2, BH), 256, 0, stream>>>(kh, vTh, projh, ctx_part, ksum_part);

    reduce_ctx<<<dim3((CTX + BH * M_ + 255) / 256), 256, 0, stream>>>(ctx_part, ksum_part, ctxTh, ksumh);

    attn_out_mfma<<<dim3(CH3, BH), 256, 0, stream>>>(qh, projh, ctxTh, ksumh, out);
}